// Round 6
// baseline (556.010 us; speedup 1.0000x reference)
//
#include <hip/hip_runtime.h>
#include <cstdint>
#include <cstddef>

// ---------------------------------------------------------------------------
// AFMADE block: 16-step autoregressive inversion of two 3-layer MADE MLPs.
// D=16, H=1024, B=2048.
// Key trick: hidden units permuted by MADE degree (deg(j)=j%15+1, fixed),
// making W1' block-lower-triangular => col-tile nt needs only ktN(nt) =
// min(nt+2,16) K-tiles (59% of MACs). Light/heavy col-tiles paired across
// the two grid halves for per-CU load balance. GEMM K-loop is double-
// buffered with a single barrier per K-tile.
//   prep_*  : bake mask * g * v/||v|| -> bf16 W0'/W1'/W2' (degree-sorted)
//   init_h0 : h0' = elu(b0')
//   loop 16x: gemm_l1f (h1' in-register + fused layer2 partial -> part)
//             step3    (reduce partials, recurrence, layer0 -> h0')
// ---------------------------------------------------------------------------

#define Dd 16
#define Hh 1024
#define Bb 2048
#define EPSV 1e-12f

typedef unsigned short u16;
typedef __attribute__((ext_vector_type(4))) float f32x4;
typedef __attribute__((ext_vector_type(8))) short s16x8;
typedef __attribute__((ext_vector_type(4))) u16 u16x4;
typedef __attribute__((ext_vector_type(8))) u16 u16x8;

__device__ __forceinline__ u16 f2bf(float f) {
  union { float f; unsigned u; } v; v.f = f;
  unsigned u = v.u;
  unsigned r = (u + 0x7fffu + ((u >> 16) & 1u)) >> 16;  // RNE
  return (u16)r;
}
__device__ __forceinline__ float bf2f(u16 u) {
  union { unsigned u; float f; } v; v.u = ((unsigned)u) << 16;
  return v.f;
}
__device__ __forceinline__ float elu(float a) {
  return a > 0.f ? a : __expf(a) - 1.f;
}
__device__ __forceinline__ void gl_lds16(const u16* g, u16* l) {
  __builtin_amdgcn_global_load_lds(
      (const __attribute__((address_space(1))) void*)g,
      (__attribute__((address_space(3))) void*)l, 16, 0, 0);
}

// Degree-sort permutation. Hidden degree group g = j%15 (deg = g+1).
// Stable sort by group: groups 0..3 have 69 members, 4..14 have 68.
// Sorted index i -> original j:
__device__ __forceinline__ int p_of(int i) {
  if (i < 276) { int g = i / 69, q = i - g * 69; return g + 15 * q; }
  int r = i - 276; int g = 4 + r / 68, q = r - (g - 4) * 68;
  return g + 15 * q;
}
// Sorted index i -> degree group g (deg = g+1), non-decreasing in i.
__device__ __forceinline__ int g_of(int i) {
  return (i < 276) ? (i / 69) : (4 + (i - 276) / 68);
}

// --------------------------- weight prep -----------------------------------

// W0'[i][d] = (g(i) >= d) * gn*v[p(i)][d]/||v[p(i)]||, plus b0s/b1-free.
// One thread per sorted (net,i). Also writes b0s (sorted f32 bias).
__global__ __launch_bounds__(256) void prep_w0(
    const float* __restrict__ v_mu, const float* __restrict__ g_mu,
    const float* __restrict__ b_mu,
    const float* __restrict__ v_lv, const float* __restrict__ g_lv,
    const float* __restrict__ b_lv,
    u16* __restrict__ W0, float* __restrict__ b0s) {
  int idx = blockIdx.x * 256 + threadIdx.x;  // 0..2047 sorted
  int net = idx >> 10, i = idx & 1023;
  int j = p_of(i), gi = g_of(i);
  const float* v = (net ? v_lv : v_mu) + j * Dd;
  float vv[16]; float ss = 0.f;
  for (int k = 0; k < 16; ++k) { vv[k] = v[k]; ss += vv[k] * vv[k]; }
  float sc = ((net ? g_lv : g_mu)[j]) * rsqrtf(ss);
  u16* o = W0 + idx * 16;
  for (int k = 0; k < 16; ++k) o[k] = f2bf((gi >= k) ? sc * vv[k] : 0.f);
  b0s[idx] = (net ? b_lv : b_mu)[j];
}

// W1'[i][k'] = (g(i) >= g(k')) * gn*v[p(i)][p(k')]/||v||. One wave per
// sorted row. Also writes b1s (sorted f32 bias).
__global__ __launch_bounds__(256) void prep_w1(
    const float* __restrict__ v_mu, const float* __restrict__ g_mu,
    const float* __restrict__ b_mu,
    const float* __restrict__ v_lv, const float* __restrict__ g_lv,
    const float* __restrict__ b_lv,
    u16* __restrict__ W1, float* __restrict__ b1s) {
  int wid = blockIdx.x * 4 + (threadIdx.x >> 6);  // 0..2047 sorted
  int l = threadIdx.x & 63;
  int net = wid >> 10, i = wid & 1023;
  int j = p_of(i), gi = g_of(i);
  const float* v = (net ? v_lv : v_mu) + (size_t)j * Hh;
  float val[4][4]; float ss = 0.f;
  for (int ii = 0; ii < 4; ++ii)
    for (int t = 0; t < 4; ++t) {
      int kp = ii * 256 + 4 * l + t;          // sorted col
      float x = v[p_of(kp)];
      val[ii][t] = x; ss += x * x;
    }
  for (int s = 32; s; s >>= 1) ss += __shfl_xor(ss, s);
  float sc = ((net ? g_lv : g_mu)[j]) * rsqrtf(ss);
  u16* o = W1 + (size_t)wid * Hh;
  for (int ii = 0; ii < 4; ++ii) {
    int k0 = ii * 256 + 4 * l;
    u16x4 w;
    for (int t = 0; t < 4; ++t)
      w[t] = f2bf((gi >= g_of(k0 + t)) ? sc * val[ii][t] : 0.f);
    *(u16x4*)(o + k0) = w;
  }
  if (l == 0) b1s[wid] = (net ? b_lv : b_mu)[j];
}

// W2'[o][k'] = (o > g(k')) * gn*v[o][p(k')]/||v||. One wave per row (32).
__global__ __launch_bounds__(256) void prep_w2(
    const float* __restrict__ v_mu, const float* __restrict__ g_mu,
    const float* __restrict__ v_lv, const float* __restrict__ g_lv,
    u16* __restrict__ W2) {
  int wid = blockIdx.x * 4 + (threadIdx.x >> 6);  // 0..31
  int l = threadIdx.x & 63;
  int net = wid >> 4, oi = wid & 15;
  const float* v = (net ? v_lv : v_mu) + (size_t)oi * Hh;
  float val[4][4]; float ss = 0.f;
  for (int ii = 0; ii < 4; ++ii)
    for (int t = 0; t < 4; ++t) {
      int kp = ii * 256 + 4 * l + t;
      float x = v[p_of(kp)];
      val[ii][t] = x; ss += x * x;
    }
  for (int s = 32; s; s >>= 1) ss += __shfl_xor(ss, s);
  float sc = ((net ? g_lv : g_mu)[oi]) * rsqrtf(ss);
  u16* o = W2 + (size_t)wid * Hh;
  for (int ii = 0; ii < 4; ++ii) {
    int k0 = ii * 256 + 4 * l;
    u16x4 w;
    for (int t = 0; t < 4; ++t)
      w[t] = f2bf((oi > g_of(k0 + t)) ? sc * val[ii][t] : 0.f);
    *(u16x4*)(o + k0) = w;
  }
}

// --------------------------- init ------------------------------------------

// h0'[net][b][i] = elu(b0s[net*1024+i])  (y == 0 at step 0)
__global__ __launch_bounds__(256) void init_h0(
    const float* __restrict__ b0s, u16* __restrict__ h0) {
  int idx = blockIdx.x * 256 + threadIdx.x;  // over 2*2048*1024
  int i = idx & 1023;
  int net = idx >> 21;
  h0[idx] = f2bf(elu(b0s[net * 1024 + i]));
}

// --------------------------- layer1 GEMM + fused layer2 partial ------------
// Sorted space. Tile 128x64, BK=64, 4 waves (2x2), wave tile 64x32,
// mfma_f32_16x16x32_bf16, double-buffered LDS, one barrier per K-tile.
// Col-tile nt needs only ktN = min(nt+2,16) K-tiles (block-triangular W1').
// Grid 512 = 2 halves x {2 nets x 16 mt x 8 jj}; half0: nt=jj (light),
// half1: nt=15-jj (heavy). CU(bid)≈bid%256 => light+heavy per CU.
__global__ __launch_bounds__(256, 2) void gemm_l1f(
    const u16* __restrict__ h0, const u16* __restrict__ W1,
    const float* __restrict__ b1s,
    const u16* __restrict__ W2,
    float* __restrict__ part) {
  __shared__ __align__(16) u16 sLds[2][128 * 64 + 64 * 64];  // 48 KiB dbuf
  __shared__ u16 sW2b[16 * 72];

  int bid = blockIdx.x;
  int q = bid & 255, half = bid >> 8;
  int net = q >> 7, r = q & 127;
  int mt = r >> 3, jj = r & 7;
  int nt = half ? (15 - jj) : jj;
  int ktN = nt + 2 < 16 ? nt + 2 : 16;
  int m0 = mt * 128, n0 = nt * 64;
  const u16* A = h0 + (size_t)net * (Bb * Hh);
  const u16* Bm = W1 + (size_t)net * (Hh * Hh);
  int tid = threadIdx.x;
  int l = tid & 63, w = tid >> 6;
  int wr = w >> 1, wc = w & 1;      // 2 x 2 wave grid
  int lr = l & 15, lk = l >> 4;
  f32x4 acc[4][2] = {};

  // stage W2 column tile (16 x 64), padded stride 72
  for (int c = 0; c < 4; ++c) {
    int e = c * 256 + tid;
    int i = e >> 6, col = e & 63;
    sW2b[i * 72 + col] = W2[(size_t)(net * 16 + i) * Hh + n0 + col];
  }
  // prologue: stage kt=0 into buf0
  {
    u16* bA = sLds[0]; u16* bB = sLds[0] + 8192;
    for (int c = 0; c < 4; ++c) {
      int qq = c * 256 + tid, row = qq >> 3, cc = qq & 7;
      gl_lds16(A + (size_t)(m0 + row) * Hh + cc * 8, bA + qq * 8);
    }
    for (int c = 0; c < 2; ++c) {
      int qq = c * 256 + tid, row = qq >> 3, cc = qq & 7;
      gl_lds16(Bm + (size_t)(n0 + row) * Hh + cc * 8, bB + qq * 8);
    }
  }
  __syncthreads();

  int cur = 0;
  for (int kt = 0; kt < ktN; ++kt) {
    if (kt + 1 < ktN) {  // stage kt+1 into the other buffer (async)
      int kb = (kt + 1) * 64;
      u16* bA = sLds[cur ^ 1]; u16* bB = sLds[cur ^ 1] + 8192;
      for (int c = 0; c < 4; ++c) {
        int qq = c * 256 + tid, row = qq >> 3, cc = qq & 7;
        gl_lds16(A + (size_t)(m0 + row) * Hh + kb + cc * 8, bA + qq * 8);
      }
      for (int c = 0; c < 2; ++c) {
        int qq = c * 256 + tid, row = qq >> 3, cc = qq & 7;
        gl_lds16(Bm + (size_t)(n0 + row) * Hh + kb + cc * 8, bB + qq * 8);
      }
    }
    const u16* bA = sLds[cur];
    const u16* bB = sLds[cur] + 8192;
    for (int kk = 0; kk < 2; ++kk) {
      int ko = kk * 32 + lk * 8;
      s16x8 af[4], bfr[2];
      for (int mi = 0; mi < 4; ++mi)
        af[mi] = *(const s16x8*)(bA + (wr * 64 + mi * 16 + lr) * 64 + ko);
      for (int ni = 0; ni < 2; ++ni)
        bfr[ni] = *(const s16x8*)(bB + (wc * 32 + ni * 16 + lr) * 64 + ko);
      for (int mi = 0; mi < 4; ++mi)
        for (int ni = 0; ni < 2; ++ni)
          acc[mi][ni] = __builtin_amdgcn_mfma_f32_16x16x32_bf16(
              af[mi], bfr[ni], acc[mi][ni], 0, 0, 0);
    }
    __syncthreads();  // drains staged loads (vmcnt0) + all LDS reads of cur
    cur ^= 1;
  }

  // epilogue: h1 tile -> LDS (stride 72), mini-GEMM vs W2 tile -> part
  {
    u16* sH = sLds[0];               // 128 x 72 = 9216 u16
    for (int ni = 0; ni < 2; ++ni) {
      int col = wc * 32 + ni * 16 + lr;
      float bias = b1s[net * 1024 + n0 + col];
      for (int mi = 0; mi < 4; ++mi)
        for (int rr = 0; rr < 4; ++rr) {
          int row = wr * 64 + mi * 16 + lk * 4 + rr;
          sH[row * 72 + col] = f2bf(elu(acc[mi][ni][rr] + bias));
        }
    }
    __syncthreads();
    f32x4 acc2[2] = {};
    for (int kk = 0; kk < 2; ++kk) {
      int ko = kk * 32 + lk * 8;
      s16x8 bfr = *(const s16x8*)(sW2b + lr * 72 + ko);
      for (int mi = 0; mi < 2; ++mi) {
        s16x8 af = *(const s16x8*)(sH + (w * 32 + mi * 16 + lr) * 72 + ko);
        acc2[mi] = __builtin_amdgcn_mfma_f32_16x16x32_bf16(
            af, bfr, acc2[mi], 0, 0, 0);
      }
    }
    for (int mi = 0; mi < 2; ++mi)
      for (int rr = 0; rr < 4; ++rr) {
        int row = m0 + w * 32 + mi * 16 + lk * 4 + rr;
        part[((size_t)(net * Bb) + row) * 256 + nt * 16 + lr] = acc2[mi][rr];
      }
  }
}

// --------------------------- partial reduce + recur + layer0 ---------------
// 2 batch rows per block, 1024 blocks x 256 threads.
__global__ __launch_bounds__(256) void step3(
    const float* __restrict__ part,
    const float* __restrict__ b2_mu, const float* __restrict__ b2_lv,
    const u16* __restrict__ W0, const float* __restrict__ b0s,
    const float* __restrict__ x,
    u16* __restrict__ h0, float* __restrict__ out, int last) {
  __shared__ float sPart[4][260];   // [r*2+net][nt*16+i], padded
  __shared__ float sOut[2][32];
  __shared__ float sY[2][16];
  int tid = threadIdx.x;
  int b0g = blockIdx.x * 2;

  {
    int seg = tid >> 6, idx = (tid & 63) * 4;  // seg = r*2+net
    int r = seg >> 1, net = seg & 1;
    const float* src = part + ((size_t)(net * Bb) + b0g + r) * 256 + idx;
    *(f32x4*)&sPart[seg][idx] = *(const f32x4*)src;
  }
  __syncthreads();
  if (tid < 64) {
    int seg = tid >> 4, i = tid & 15;
    int r = seg >> 1, net = seg & 1;
    float s = 0.f;
    for (int ntc = 0; ntc < 16; ++ntc) s += sPart[seg][ntc * 16 + i];
    sOut[r][net * 16 + i] = s + (net ? b2_lv : b2_mu)[i];
  }
  __syncthreads();

  if (tid < 32) {
    int r = tid >> 4, d = tid & 15;
    int b = b0g + r;
    float mu = sOut[r][d];
    float ls = 0.5f * sOut[r][16 + d];
    float yn = (x[b * 16 + d] - mu) / (__expf(ls) + EPSV);
    sY[r][d] = yn;
    if (last) {
      out[b * 16 + d] = yn;
      float pp = ls;
      pp += __shfl_xor(pp, 1);
      pp += __shfl_xor(pp, 2);
      pp += __shfl_xor(pp, 4);
      pp += __shfl_xor(pp, 8);
      if (d == 0) out[Bb * 16 + b] = pp;
    }
  }
  __syncthreads();

  if (!last) {
    for (int it = 0; it < 8; ++it) {
      int jj = it * 256 + tid;      // 0..2047 sorted
      int net = jj >> 10;
      u16x8 wa = *(const u16x8*)(W0 + jj * 16);
      u16x8 wb = *(const u16x8*)(W0 + jj * 16 + 8);
      float wk[16];
      for (int tt = 0; tt < 8; ++tt) {
        wk[tt] = bf2f(wa[tt]); wk[8 + tt] = bf2f(wb[tt]);
      }
      float bias = b0s[jj];
      u16* hp = h0 + (size_t)net * (Bb * Hh) + (jj & 1023);
      for (int r = 0; r < 2; ++r) {
        float a = bias;
        for (int k = 0; k < 16; ++k) a += sY[r][k] * wk[k];
        hp[(size_t)(b0g + r) * Hh] = f2bf(elu(a));
      }
    }
  }
}

// --------------------------- launch ----------------------------------------

extern "C" void kernel_launch(void* const* d_in, const int* in_sizes, int n_in,
                              void* d_out, int out_size, void* d_ws, size_t ws_size,
                              hipStream_t stream) {
  const float* x     = (const float*)d_in[0];
  const float* mu_v0 = (const float*)d_in[1];
  const float* mu_g0 = (const float*)d_in[2];
  const float* mu_b0 = (const float*)d_in[3];
  const float* mu_v1 = (const float*)d_in[4];
  const float* mu_g1 = (const float*)d_in[5];
  const float* mu_b1 = (const float*)d_in[6];
  const float* mu_v2 = (const float*)d_in[7];
  const float* mu_g2 = (const float*)d_in[8];
  const float* mu_b2 = (const float*)d_in[9];
  const float* lv_v0 = (const float*)d_in[10];
  const float* lv_g0 = (const float*)d_in[11];
  const float* lv_b0 = (const float*)d_in[12];
  const float* lv_v1 = (const float*)d_in[13];
  const float* lv_g1 = (const float*)d_in[14];
  const float* lv_b1 = (const float*)d_in[15];
  const float* lv_v2 = (const float*)d_in[16];
  const float* lv_g2 = (const float*)d_in[17];
  const float* lv_b2 = (const float*)d_in[18];

  char* ws = (char*)d_ws;
  u16*   W1   = (u16*)(ws);                            // 4 MiB
  u16*   W0   = (u16*)(ws + (4u << 20));               // 64 KiB
  u16*   W2   = (u16*)(ws + (4u << 20) + 65536);       // 64 KiB
  float* b0s  = (float*)(ws + (4u << 20) + 131072);    // 8 KiB
  float* b1s  = (float*)(ws + (4u << 20) + 139264);    // 8 KiB
  u16*   h0   = (u16*)(ws + (4u << 20) + 147456);      // 8 MiB
  float* part = (float*)(ws + (12u << 20) + 147456);   // 4 MiB

  prep_w0<<<8, 256, 0, stream>>>(mu_v0, mu_g0, mu_b0, lv_v0, lv_g0, lv_b0,
                                 W0, b0s);
  prep_w1<<<512, 256, 0, stream>>>(mu_v1, mu_g1, mu_b1, lv_v1, lv_g1, lv_b1,
                                   W1, b1s);
  prep_w2<<<8, 256, 0, stream>>>(mu_v2, mu_g2, lv_v2, lv_g2, W2);
  init_h0<<<16384, 256, 0, stream>>>(b0s, h0);

  for (int s = 0; s < 16; ++s) {
    gemm_l1f<<<512, 256, 0, stream>>>(h0, W1, b1s, W2, part);
    step3<<<1024, 256, 0, stream>>>(part, mu_b2, lv_b2, W0, b0s,
                                    x, h0, (float*)d_out, s == 15 ? 1 : 0);
  }
}